// Round 6
// baseline (175.564 us; speedup 1.0000x reference)
//
#include <hip/hip_runtime.h>
#include <hip/hip_bf16.h>

#define D_MODEL 1024
#define ATT_DIM 64
#define BATCH 8
#define SEQ 2048
#define MROWS (BATCH * SEQ)  // 16384

typedef short bf16x8 __attribute__((ext_vector_type(8)));
typedef float f32x4 __attribute__((ext_vector_type(4)));

#define MFMA16(a, b, c) __builtin_amdgcn_mfma_f32_16x16x32_bf16((a), (b), (c), 0, 0, 0)

__device__ inline short f2bf(float f) {
    union { __hip_bfloat16 h; short s; } u;
    u.h = __float2bfloat16(f);  // RNE
    return u.s;
}

__device__ __forceinline__ void gload_lds16(const float* g, float* l) {
    __builtin_amdgcn_global_load_lds(
        (const __attribute__((address_space(1))) void*)g,
        (__attribute__((address_space(3))) void*)l, 16, 0, 0);
}

// ---------------------------------------------------------------------------
// K0: convert Wq,Wk,Wv fp32 -> bf16 workspace [3][64][1024].
// Wq pre-scaled by 1/64 (exact pow2) so MFMA output == scores.
// ---------------------------------------------------------------------------
__global__ __launch_bounds__(256) void wcvt_kernel(
    const float* __restrict__ Wq, const float* __restrict__ Wk,
    const float* __restrict__ Wv, short* __restrict__ Wbf)
{
    const int idx = blockIdx.x * 256 + threadIdx.x;   // 24576 threads
    const int per = ATT_DIM * D_MODEL;                // 65536
    const int base = idx * 8;
    const int mi = base / per;
    const int off = base - mi * per;
    const float* src = (mi == 0) ? Wq : (mi == 1 ? Wk : Wv);
    const float sc = (mi == 0) ? (1.0f / 64.0f) : 1.0f;
    const float4 a = *reinterpret_cast<const float4*>(src + off);
    const float4 b = *reinterpret_cast<const float4*>(src + off + 4);
    bf16x8 r;
    r[0] = f2bf(a.x * sc); r[1] = f2bf(a.y * sc);
    r[2] = f2bf(a.z * sc); r[3] = f2bf(a.w * sc);
    r[4] = f2bf(b.x * sc); r[5] = f2bf(b.y * sc);
    r[6] = f2bf(b.z * sc); r[7] = f2bf(b.w * sc);
    *reinterpret_cast<bf16x8*>(Wbf + base) = r;
}

// ---------------------------------------------------------------------------
// K1: projections via MFMA with global_load_lds A-streaming.
// Block = 256 thr = 4 waves, 64 rows; K-chunks of 64 fp32, double-buffered
// LDS (2 x 16 KB). A-tile XOR-swizzled (byte ^= (row&7)<<4) on BOTH the
// global source address (stage) and the ds_read address (rule #21).
// W (bf16, L2-resident) read straight from global per fragment.
// V output stored transposed: vpT[b][e][s] bf16.
// ---------------------------------------------------------------------------
__global__ __launch_bounds__(256) void proj_mfma_kernel(
    const float* __restrict__ q, const float* __restrict__ k,
    const float* __restrict__ v, const short* __restrict__ Wbf,
    short* __restrict__ qp, short* __restrict__ kp, short* __restrict__ vpT)
{
    const int mat = blockIdx.y;  // 0:q 1:k 2:v
    const float* x = (mat == 0) ? q : (mat == 1 ? k : v);
    const short* W = Wbf + mat * ATT_DIM * D_MODEL;

    __shared__ float As[2][4096];   // [buf][64 rows x 64 cols], swizzled

    const int tid = threadIdx.x;
    const int w = tid >> 6;
    const int l = tid & 63;
    const int lr = l & 15;
    const int g = l >> 4;

    const int m0 = blockIdx.x * 64;
    const int row = w * 16 + lr;          // this lane's fragment row
    const int xr = (row & 7) << 4;        // read-side XOR (bytes)

    f32x4 acc[4] = {};

    // --- staging: wave w, issue j covers LDS bytes [(w*4+j)*1024, +1024) ---
    // lane l -> lds slot base + l*16 (HW); global row rs, 16B col lr (swizzled)
    #define STAGE(c, buf)                                                      \
        {                                                                      \
            const int kt_ = (c) * 64;                                          \
            _Pragma("unroll")                                                  \
            for (int j = 0; j < 4; ++j) {                                      \
                const int rs = (w * 4 + j) * 4 + g;                            \
                const int scb = (lr * 16) ^ ((rs & 7) << 4);                   \
                gload_lds16(x + (long)(m0 + rs) * D_MODEL + kt_ + (scb >> 2),  \
                            &As[buf][(w * 4 + j) * 256]);                      \
            }                                                                  \
        }

    STAGE(0, 0);
    __syncthreads();

    for (int c = 0; c < 16; ++c) {
        const int buf = c & 1;
        if (c < 15) STAGE(c + 1, buf ^ 1);

        const int kt = c * 64;
        const char* Ab = (const char*)&As[buf][0] + row * 256;
        #pragma unroll
        for (int ks = 0; ks < 2; ++ks) {
            const int b0 = ks * 128 + g * 32;
            const float4 a0 = *reinterpret_cast<const float4*>(Ab + (b0 ^ xr));
            const float4 a1 = *reinterpret_cast<const float4*>(Ab + ((b0 + 16) ^ xr));
            bf16x8 af;
            af[0] = f2bf(a0.x); af[1] = f2bf(a0.y); af[2] = f2bf(a0.z); af[3] = f2bf(a0.w);
            af[4] = f2bf(a1.x); af[5] = f2bf(a1.y); af[6] = f2bf(a1.z); af[7] = f2bf(a1.w);
            #pragma unroll
            for (int ef = 0; ef < 4; ++ef) {
                const bf16x8 wf = *reinterpret_cast<const bf16x8*>(
                    W + (ef * 16 + lr) * D_MODEL + kt + ks * 32 + g * 8);
                acc[ef] = MFMA16(af, wf, acc[ef]);
            }
        }
        __syncthreads();   // drains vmcnt (stage c+1 landed) + read-done sync
    }
    #undef STAGE

    // D layout: row = m0 + w*16 + g*4 + j, col = lr (within 16-col tile ef)
    if (mat < 2) {
        short* out = (mat == 0) ? qp : kp;
        #pragma unroll
        for (int ef = 0; ef < 4; ++ef)
            #pragma unroll
            for (int j = 0; j < 4; ++j)
                out[(long)(m0 + w * 16 + g * 4 + j) * ATT_DIM + ef * 16 + lr] =
                    f2bf(acc[ef][j]);
    } else {
        const int b = m0 / SEQ;                   // 64-row block never straddles batch
        const int s0 = (m0 - b * SEQ) + w * 16;
        #pragma unroll
        for (int ef = 0; ef < 4; ++ef)
            #pragma unroll
            for (int j = 0; j < 4; ++j)
                vpT[((long)b * ATT_DIM + ef * 16 + lr) * SEQ + s0 + g * 4 + j] =
                    f2bf(acc[ef][j]);
    }
}

// ---------------------------------------------------------------------------
// K2: fused scores+softmax+PV, RECOMPUTE variant (low-VGPR, high-occupancy).
// Block = 512 thr = 8 waves; QBLK=16; wave w owns k-range [w*256,(w+1)*256).
// Pass A: QK^T MFMA per 32-k chunk, ONLINE (m,l) per q-row (chunk s regs
// discarded -> no 64-reg score panel). Lane merge (16-lane shfl), then a
// SINGLE barrier for the cross-wave (m,l) merge. Pass B: recompute QK^T
// (K frags are L2-hot), write normalized probs, PV via per-wave LDS
// transpose, MFMA accumulate. O merged across waves in LDS (union).
// __launch_bounds__(512, 8) forces VGPR<=64 -> 8 waves/SIMD (m69 threshold).
// ---------------------------------------------------------------------------
union AttnSmem {
    struct {
        short p[8][16][40];   // per-wave P transpose tile (80B row, 16B aligned)
        float m[8][16];
        float l[8][16];
    } a;
    float o[8][64][17];       // per-wave O^T for final merge
};

__global__ __launch_bounds__(512, 8) void attn_kernel(
    const short* __restrict__ qp, const short* __restrict__ kp,
    const short* __restrict__ vpT, float* __restrict__ probs,
    float* __restrict__ att)
{
    __shared__ AttnSmem lds;

    const int tid = threadIdx.x;
    const int w = tid >> 6;    // 0..7
    const int l = tid & 63;
    const int lr = l & 15;
    const int g = l >> 4;

    const int b = blockIdx.y;
    const int q0 = blockIdx.x * 16;

    const short* qpb = qp + ((long)b * SEQ + q0) * ATT_DIM;
    const short* kpb = kp + (long)b * SEQ * ATT_DIM;
    const short* vTb = vpT + (long)b * ATT_DIM * SEQ;

    const bf16x8 qa0 = *reinterpret_cast<const bf16x8*>(qpb + lr * ATT_DIM + g * 8);
    const bf16x8 qa1 = *reinterpret_cast<const bf16x8*>(qpb + lr * ATT_DIM + 32 + g * 8);

    const int kbeg = w * 256;

    // ---------------- pass A: QK^T + online (m,l); s discarded ----------------
    float m[4] = {-1e30f, -1e30f, -1e30f, -1e30f};
    float lsum[4] = {0.f, 0.f, 0.f, 0.f};

    for (int ch = 0; ch < 8; ++ch) {
        const short* kb = kpb + (long)(kbeg + ch * 32) * ATT_DIM;
        const bf16x8 kb00 = *reinterpret_cast<const bf16x8*>(kb + lr * ATT_DIM + g * 8);
        const bf16x8 kb01 = *reinterpret_cast<const bf16x8*>(kb + lr * ATT_DIM + 32 + g * 8);
        const bf16x8 kb10 = *reinterpret_cast<const bf16x8*>(kb + (16 + lr) * ATT_DIM + g * 8);
        const bf16x8 kb11 = *reinterpret_cast<const bf16x8*>(kb + (16 + lr) * ATT_DIM + 32 + g * 8);
        f32x4 t0 = {}; t0 = MFMA16(qa0, kb00, t0); t0 = MFMA16(qa1, kb01, t0);
        f32x4 t1 = {}; t1 = MFMA16(qa0, kb10, t1); t1 = MFMA16(qa1, kb11, t1);
        #pragma unroll
        for (int j = 0; j < 4; ++j) {
            const float cm = fmaxf(t0[j], t1[j]);
            const float mn = fmaxf(m[j], cm);
            lsum[j] = lsum[j] * __expf(m[j] - mn) +
                      __expf(t0[j] - mn) + __expf(t1[j] - mn);
            m[j] = mn;
        }
    }

    // lane merge within each 16-lane k-column group
    #pragma unroll
    for (int j = 0; j < 4; ++j) {
        float mj = m[j];
        mj = fmaxf(mj, __shfl_xor(mj, 1));
        mj = fmaxf(mj, __shfl_xor(mj, 2));
        mj = fmaxf(mj, __shfl_xor(mj, 4));
        mj = fmaxf(mj, __shfl_xor(mj, 8));
        float lj = lsum[j] * __expf(m[j] - mj);
        lj += __shfl_xor(lj, 1);
        lj += __shfl_xor(lj, 2);
        lj += __shfl_xor(lj, 4);
        lj += __shfl_xor(lj, 8);
        m[j] = mj; lsum[j] = lj;
    }
    if (lr == 0) {
        #pragma unroll
        for (int j = 0; j < 4; ++j) {
            lds.a.m[w][g * 4 + j] = m[j];
            lds.a.l[w][g * 4 + j] = lsum[j];
        }
    }
    __syncthreads();   // single barrier: both m and l published

    float gm[4], invl[4];
    #pragma unroll
    for (int j = 0; j < 4; ++j) {
        const int qr = g * 4 + j;
        float mf = lds.a.m[0][qr];
        #pragma unroll
        for (int ww = 1; ww < 8; ++ww) mf = fmaxf(mf, lds.a.m[ww][qr]);
        float lf = 0.f;
        #pragma unroll
        for (int ww = 0; ww < 8; ++ww)
            lf += lds.a.l[ww][qr] * __expf(lds.a.m[ww][qr] - mf);
        gm[j] = mf;
        invl[j] = 1.0f / lf;
    }

    // ---------------- pass B: recompute QK^T, write probs, PV ----------------
    f32x4 accO[4] = {};
    float* pbase = probs + ((long)b * SEQ + q0) * SEQ;

    for (int ch = 0; ch < 8; ++ch) {
        const int k0 = kbeg + ch * 32;
        const short* kb = kpb + (long)k0 * ATT_DIM;
        const bf16x8 kb00 = *reinterpret_cast<const bf16x8*>(kb + lr * ATT_DIM + g * 8);
        const bf16x8 kb01 = *reinterpret_cast<const bf16x8*>(kb + lr * ATT_DIM + 32 + g * 8);
        const bf16x8 kb10 = *reinterpret_cast<const bf16x8*>(kb + (16 + lr) * ATT_DIM + g * 8);
        const bf16x8 kb11 = *reinterpret_cast<const bf16x8*>(kb + (16 + lr) * ATT_DIM + 32 + g * 8);
        f32x4 t0 = {}; t0 = MFMA16(qa0, kb00, t0); t0 = MFMA16(qa1, kb01, t0);
        f32x4 t1 = {}; t1 = MFMA16(qa0, kb10, t1); t1 = MFMA16(qa1, kb11, t1);

        #pragma unroll
        for (int j = 0; j < 4; ++j) {
            const int qr = g * 4 + j;
            const float p0 = __expf(t0[j] - gm[j]) * invl[j];
            const float p1 = __expf(t1[j] - gm[j]) * invl[j];
            pbase[(long)qr * SEQ + k0 + lr] = p0;
            pbase[(long)qr * SEQ + k0 + 16 + lr] = p1;
            lds.a.p[w][qr][lr] = f2bf(p0);
            lds.a.p[w][qr][16 + lr] = f2bf(p1);
        }
        // B-frag for PV: pb[i] = P[q=lr][k-local = 8g+i]  (wave-local LDS RAW)
        const bf16x8 pb = *reinterpret_cast<const bf16x8*>(&lds.a.p[w][lr][g * 8]);
        #pragma unroll
        for (int ef = 0; ef < 4; ++ef) {
            const bf16x8 va = *reinterpret_cast<const bf16x8*>(
                vTb + (long)(ef * 16 + lr) * SEQ + k0 + g * 8);
            accO[ef] = MFMA16(va, pb, accO[ef]);
        }
    }

    // ---------------- merge O across waves ----------------
    __syncthreads();   // lds.a dead; union now used as lds.o
    #pragma unroll
    for (int ef = 0; ef < 4; ++ef)
        #pragma unroll
        for (int j = 0; j < 4; ++j)
            lds.o[w][ef * 16 + g * 4 + j][lr] = accO[ef][j];
    __syncthreads();

    {
        const int qr = tid >> 5;          // 0..15
        const int e0 = (tid & 31) * 2;    // 0..62
        float o0 = 0.f, o1 = 0.f;
        #pragma unroll
        for (int ww = 0; ww < 8; ++ww) {
            o0 += lds.o[ww][e0][qr];
            o1 += lds.o[ww][e0 + 1][qr];
        }
        float2 o = make_float2(o0, o1);
        *reinterpret_cast<float2*>(att + ((long)b * SEQ + q0 + qr) * ATT_DIM + e0) = o;
    }
}

// ---------------------------------------------------------------------------
extern "C" void kernel_launch(void* const* d_in, const int* in_sizes, int n_in,
                              void* d_out, int out_size, void* d_ws, size_t ws_size,
                              hipStream_t stream)
{
    const float* q  = (const float*)d_in[0];
    const float* k  = (const float*)d_in[1];
    const float* v  = (const float*)d_in[2];
    const float* Wq = (const float*)d_in[3];
    const float* Wk = (const float*)d_in[4];
    const float* Wv = (const float*)d_in[5];

    float* att   = (float*)d_out;                        // [B,S,64]
    float* probs = att + (size_t)BATCH * SEQ * ATT_DIM;  // [B,S,S]

    short* qp  = (short*)d_ws;                    // [B*S,64] bf16 (Wq pre-scaled 1/64)
    short* kp  = qp + (size_t)MROWS * ATT_DIM;    // [B*S,64] bf16
    short* vpT = kp + (size_t)MROWS * ATT_DIM;    // [B][64][S] bf16
    short* Wbf = vpT + (size_t)MROWS * ATT_DIM;   // [3][64][1024] bf16

    wcvt_kernel<<<dim3(96), 256, 0, stream>>>(Wq, Wk, Wv, Wbf);

    proj_mfma_kernel<<<dim3(MROWS / 64, 3), 256, 0, stream>>>(
        q, k, v, Wbf, qp, kp, vpT);

    attn_kernel<<<dim3(SEQ / 16, BATCH), 512, 0, stream>>>(
        qp, kp, vpT, probs, att);
}

// Round 7
// 151.222 us; speedup vs baseline: 1.1610x; 1.1610x over previous
//
#include <hip/hip_runtime.h>
#include <hip/hip_bf16.h>

#define D_MODEL 1024
#define ATT_DIM 64
#define BATCH 8
#define SEQ 2048
#define MROWS (BATCH * SEQ)  // 16384

typedef short bf16x8 __attribute__((ext_vector_type(8)));
typedef float f32x4 __attribute__((ext_vector_type(4)));
typedef long lx2 __attribute__((ext_vector_type(2)));

#define MFMA16(a, b, c) __builtin_amdgcn_mfma_f32_16x16x32_bf16((a), (b), (c), 0, 0, 0)

__device__ inline short f2bf(float f) {
    union { __hip_bfloat16 h; short s; } u;
    u.h = __float2bfloat16(f);  // RNE
    return u.s;
}

// pack two f32 -> one dword of 2 bf16 (RNE), T12 primitive (no builtin, m240)
__device__ __forceinline__ unsigned cvtpk(float lo, float hi) {
    unsigned r;
    asm("v_cvt_pk_bf16_f32 %0, %1, %2" : "=v"(r) : "v"(lo), "v"(hi));
    return r;
}

__device__ __forceinline__ void gload_lds16(const float* g, float* l) {
    __builtin_amdgcn_global_load_lds(
        (const __attribute__((address_space(1))) void*)g,
        (__attribute__((address_space(3))) void*)l, 16, 0, 0);
}

// ---------------------------------------------------------------------------
// K0: convert Wq,Wk,Wv fp32 -> bf16 workspace [3][64][1024].
// Wq pre-scaled by 1/64 (exact pow2) so MFMA output == scores.
// ---------------------------------------------------------------------------
__global__ __launch_bounds__(256) void wcvt_kernel(
    const float* __restrict__ Wq, const float* __restrict__ Wk,
    const float* __restrict__ Wv, short* __restrict__ Wbf)
{
    const int idx = blockIdx.x * 256 + threadIdx.x;   // 24576 threads
    const int per = ATT_DIM * D_MODEL;                // 65536
    const int base = idx * 8;
    const int mi = base / per;
    const int off = base - mi * per;
    const float* src = (mi == 0) ? Wq : (mi == 1 ? Wk : Wv);
    const float sc = (mi == 0) ? (1.0f / 64.0f) : 1.0f;
    const float4 a = *reinterpret_cast<const float4*>(src + off);
    const float4 b = *reinterpret_cast<const float4*>(src + off + 4);
    bf16x8 r;
    r[0] = f2bf(a.x * sc); r[1] = f2bf(a.y * sc);
    r[2] = f2bf(a.z * sc); r[3] = f2bf(a.w * sc);
    r[4] = f2bf(b.x * sc); r[5] = f2bf(b.y * sc);
    r[6] = f2bf(b.z * sc); r[7] = f2bf(b.w * sc);
    *reinterpret_cast<bf16x8*>(Wbf + base) = r;
}

// ---------------------------------------------------------------------------
// K1: projections via MFMA with global_load_lds A-streaming + register
// prefetch of next chunk's W fragments (so the pre-barrier vmcnt(0) drain
// absorbs W-load latency; compute phase is LDS+reg only).
// ---------------------------------------------------------------------------
__global__ __launch_bounds__(256) void proj_mfma_kernel(
    const float* __restrict__ q, const float* __restrict__ k,
    const float* __restrict__ v, const short* __restrict__ Wbf,
    short* __restrict__ qp, short* __restrict__ kp, short* __restrict__ vpT)
{
    const int mat = blockIdx.y;  // 0:q 1:k 2:v
    const float* x = (mat == 0) ? q : (mat == 1 ? k : v);
    const short* W = Wbf + mat * ATT_DIM * D_MODEL;

    __shared__ float As[2][4096];   // [buf][64 rows x 64 cols], swizzled

    const int tid = threadIdx.x;
    const int w = tid >> 6;
    const int l = tid & 63;
    const int lr = l & 15;
    const int g = l >> 4;

    const int m0 = blockIdx.x * 64;
    const int row = w * 16 + lr;          // this lane's fragment row
    const int xr = (row & 7) << 4;        // read-side XOR (bytes)

    f32x4 acc[4] = {};

    #define STAGE(c, buf)                                                      \
        {                                                                      \
            const int kt_ = (c) * 64;                                          \
            _Pragma("unroll")                                                  \
            for (int j = 0; j < 4; ++j) {                                      \
                const int rs = (w * 4 + j) * 4 + g;                            \
                const int scb = (lr * 16) ^ ((rs & 7) << 4);                   \
                gload_lds16(x + (long)(m0 + rs) * D_MODEL + kt_ + (scb >> 2),  \
                            &As[buf][(w * 4 + j) * 256]);                      \
            }                                                                  \
        }

    // W frag i = ks*4+ef for chunk c
    #define WFRAG(c, ks, ef)                                                   \
        (*reinterpret_cast<const bf16x8*>(                                     \
            W + ((ef) * 16 + lr) * D_MODEL + (c) * 64 + (ks) * 32 + g * 8))

    bf16x8 wreg[8];
    #pragma unroll
    for (int ks = 0; ks < 2; ++ks)
        #pragma unroll
        for (int ef = 0; ef < 4; ++ef) wreg[ks * 4 + ef] = WFRAG(0, ks, ef);

    STAGE(0, 0);
    __syncthreads();

    for (int c = 0; c < 16; ++c) {
        const int buf = c & 1;
        bf16x8 wnext[8];
        if (c < 15) {
            STAGE(c + 1, buf ^ 1);
            #pragma unroll
            for (int ks = 0; ks < 2; ++ks)
                #pragma unroll
                for (int ef = 0; ef < 4; ++ef)
                    wnext[ks * 4 + ef] = WFRAG(c + 1, ks, ef);
        }

        const char* Ab = (const char*)&As[buf][0] + row * 256;
        #pragma unroll
        for (int ks = 0; ks < 2; ++ks) {
            const int b0 = ks * 128 + g * 32;
            const float4 a0 = *reinterpret_cast<const float4*>(Ab + (b0 ^ xr));
            const float4 a1 = *reinterpret_cast<const float4*>(Ab + ((b0 + 16) ^ xr));
            bf16x8 af;
            af[0] = f2bf(a0.x); af[1] = f2bf(a0.y); af[2] = f2bf(a0.z); af[3] = f2bf(a0.w);
            af[4] = f2bf(a1.x); af[5] = f2bf(a1.y); af[6] = f2bf(a1.z); af[7] = f2bf(a1.w);
            #pragma unroll
            for (int ef = 0; ef < 4; ++ef)
                acc[ef] = MFMA16(af, wreg[ks * 4 + ef], acc[ef]);
        }
        __syncthreads();   // vmcnt(0)+barrier: A-stage AND wnext both land here
        if (c < 15) {
            #pragma unroll
            for (int i = 0; i < 8; ++i) wreg[i] = wnext[i];
        }
    }
    #undef STAGE
    #undef WFRAG

    if (mat < 2) {
        short* out = (mat == 0) ? qp : kp;
        #pragma unroll
        for (int ef = 0; ef < 4; ++ef)
            #pragma unroll
            for (int j = 0; j < 4; ++j)
                out[(long)(m0 + w * 16 + g * 4 + j) * ATT_DIM + ef * 16 + lr] =
                    f2bf(acc[ef][j]);
    } else {
        const int b = m0 / SEQ;
        const int s0 = (m0 - b * SEQ) + w * 16;
        #pragma unroll
        for (int ef = 0; ef < 4; ++ef)
            #pragma unroll
            for (int j = 0; j < 4; ++j)
                vpT[((long)b * ATT_DIM + ef * 16 + lr) * SEQ + s0 + g * 4 + j] =
                    f2bf(acc[ef][j]);
    }
}

// ---------------------------------------------------------------------------
// K2: fused scores+softmax+PV, SWAPPED-QK^T register-panel variant.
// Block = 512 thr = 8 waves; QBLK=16; wave w owns k-range [w*256,(w+1)*256).
// mfma(K,Q) -> D[k][q]: lane (g,lr) holds S[k0+ (h*16) + g*4+j][q0+lr].
//  - probs stores are direct float4 from the accumulator (16 instrs/thread)
//  - softmax state is scalar/thread (q=lr); reduce = 2 shfl_xor + 1 barrier
//  - PV B-frag via 4 cvt_pk + 1 ds_write_b128 + 2 ds_read_b64 per chunk
// ---------------------------------------------------------------------------
union AttnSmem {
    short pk[8][16][40];   // [wave][q=lr][4 src-groups x 4 dwords], 80B rows
    float o[8][64][17];    // [wave][e][q] for final merge
};

__global__ __launch_bounds__(512) void attn_kernel(
    const short* __restrict__ qp, const short* __restrict__ kp,
    const short* __restrict__ vpT, float* __restrict__ probs,
    float* __restrict__ att)
{
    __shared__ __align__(16) AttnSmem u;
    __shared__ float stats_m[8][16];
    __shared__ float stats_l[8][16];

    const int tid = threadIdx.x;
    const int w = tid >> 6;    // 0..7
    const int l = tid & 63;
    const int lr = l & 15;
    const int g = l >> 4;

    const int b = blockIdx.y;
    const int q0 = blockIdx.x * 16;

    const short* qpb = qp + ((long)b * SEQ + q0) * ATT_DIM;
    const short* kpb = kp + (long)b * SEQ * ATT_DIM;
    const short* vTb = vpT + (long)b * ATT_DIM * SEQ;

    const bf16x8 qa0 = *reinterpret_cast<const bf16x8*>(qpb + lr * ATT_DIM + g * 8);
    const bf16x8 qa1 = *reinterpret_cast<const bf16x8*>(qpb + lr * ATT_DIM + 32 + g * 8);

    const int kbeg = w * 256;

    // ---------------- pass A: swapped QK^T (pure loads+MFMA) ----------------
    f32x4 s[8][2];
    #pragma unroll
    for (int ch = 0; ch < 8; ++ch) {
        const short* kb = kpb + (long)(kbeg + ch * 32) * ATT_DIM;
        const bf16x8 kb00 = *reinterpret_cast<const bf16x8*>(kb + lr * ATT_DIM + g * 8);
        const bf16x8 kb01 = *reinterpret_cast<const bf16x8*>(kb + lr * ATT_DIM + 32 + g * 8);
        const bf16x8 kb10 = *reinterpret_cast<const bf16x8*>(kb + (16 + lr) * ATT_DIM + g * 8);
        const bf16x8 kb11 = *reinterpret_cast<const bf16x8*>(kb + (16 + lr) * ATT_DIM + 32 + g * 8);
        f32x4 t0 = {}; t0 = MFMA16(kb00, qa0, t0); t0 = MFMA16(kb01, qa1, t0);
        f32x4 t1 = {}; t1 = MFMA16(kb10, qa0, t1); t1 = MFMA16(kb11, qa1, t1);
        s[ch][0] = t0; s[ch][1] = t1;
    }

    // ---------------- softmax (scalar state per thread, q = lr) -------------
    float mw = -1e30f;
    #pragma unroll
    for (int ch = 0; ch < 8; ++ch)
        #pragma unroll
        for (int h = 0; h < 2; ++h)
            mw = fmaxf(mw, fmaxf(fmaxf(s[ch][h][0], s[ch][h][1]),
                                 fmaxf(s[ch][h][2], s[ch][h][3])));
    mw = fmaxf(mw, __shfl_xor(mw, 16));
    mw = fmaxf(mw, __shfl_xor(mw, 32));

    float lw = 0.f;
    #pragma unroll
    for (int ch = 0; ch < 8; ++ch)
        #pragma unroll
        for (int h = 0; h < 2; ++h)
            #pragma unroll
            for (int j = 0; j < 4; ++j) {
                const float e = __expf(s[ch][h][j] - mw);
                s[ch][h][j] = e;
                lw += e;
            }
    lw += __shfl_xor(lw, 16);
    lw += __shfl_xor(lw, 32);

    if (l < 16) { stats_m[w][l] = mw; stats_l[w][l] = lw; }
    __syncthreads();   // single softmax barrier

    float gm = stats_m[0][lr];
    #pragma unroll
    for (int ww = 1; ww < 8; ++ww) gm = fmaxf(gm, stats_m[ww][lr]);
    float tot = 0.f;
    #pragma unroll
    for (int ww = 0; ww < 8; ++ww)
        tot += stats_l[ww][lr] * __expf(stats_m[ww][lr] - gm);
    const float scale = __expf(mw - gm) / tot;   // folds wave->global correction
    #pragma unroll
    for (int ch = 0; ch < 8; ++ch)
        #pragma unroll
        for (int h = 0; h < 2; ++h)
            s[ch][h] *= scale;

    // ---------------- pass B: float4 probs stores + PV ----------------------
    f32x4 accO[4] = {};
    float* pbase = probs + ((long)b * SEQ + q0 + lr) * SEQ;   // row q = q0+lr

    #pragma unroll
    for (int ch = 0; ch < 8; ++ch) {
        const int k0 = kbeg + ch * 32;
        // direct vector stores of the normalized panel
        *reinterpret_cast<f32x4*>(pbase + k0 + g * 4)      = s[ch][0];
        *reinterpret_cast<f32x4*>(pbase + k0 + 16 + g * 4) = s[ch][1];

        // pack own 8 k-values (klocal 4g..4g+3 and 16+4g..16+4g+3) to bf16
        uint4 cc;
        cc.x = cvtpk(s[ch][0][0], s[ch][0][1]);
        cc.y = cvtpk(s[ch][0][2], s[ch][0][3]);
        cc.z = cvtpk(s[ch][1][0], s[ch][1][1]);
        cc.w = cvtpk(s[ch][1][2], s[ch][1][3]);
        *reinterpret_cast<uint4*>(&u.pk[w][lr][g * 8]) = cc;   // ds_write_b128

        // gather B-frag: pb[i] = P[k0+8g+i][q0+lr] (wave-local RAW, lgkm wait)
        const long lo = *reinterpret_cast<const long*>(
            &u.pk[w][lr][(2 * (g & 1)) * 8 + (g >> 1) * 4]);
        const long hi = *reinterpret_cast<const long*>(
            &u.pk[w][lr][(2 * (g & 1) + 1) * 8 + (g >> 1) * 4]);
        union { lx2 l2; bf16x8 v; } pbu;
        pbu.l2[0] = lo; pbu.l2[1] = hi;
        const bf16x8 pb = pbu.v;

        #pragma unroll
        for (int ef = 0; ef < 4; ++ef) {
            const bf16x8 va = *reinterpret_cast<const bf16x8*>(
                vTb + (long)(ef * 16 + lr) * SEQ + k0 + g * 8);
            accO[ef] = MFMA16(va, pb, accO[ef]);
        }
    }

    // ---------------- merge O across waves ----------------
    __syncthreads();   // pk reads done in all waves; union becomes o
    #pragma unroll
    for (int ef = 0; ef < 4; ++ef)
        #pragma unroll
        for (int j = 0; j < 4; ++j)
            u.o[w][ef * 16 + g * 4 + j][lr] = accO[ef][j];
    __syncthreads();

    {
        const int qr = tid >> 5;          // 0..15
        const int e0 = (tid & 31) * 2;    // 0..62
        float o0 = 0.f, o1 = 0.f;
        #pragma unroll
        for (int ww = 0; ww < 8; ++ww) {
            o0 += u.o[ww][e0][qr];
            o1 += u.o[ww][e0 + 1][qr];
        }
        float2 o = make_float2(o0, o1);
        *reinterpret_cast<float2*>(att + ((long)b * SEQ + q0 + qr) * ATT_DIM + e0) = o;
    }
}

// ---------------------------------------------------------------------------
extern "C" void kernel_launch(void* const* d_in, const int* in_sizes, int n_in,
                              void* d_out, int out_size, void* d_ws, size_t ws_size,
                              hipStream_t stream)
{
    const float* q  = (const float*)d_in[0];
    const float* k  = (const float*)d_in[1];
    const float* v  = (const float*)d_in[2];
    const float* Wq = (const float*)d_in[3];
    const float* Wk = (const float*)d_in[4];
    const float* Wv = (const float*)d_in[5];

    float* att   = (float*)d_out;                        // [B,S,64]
    float* probs = att + (size_t)BATCH * SEQ * ATT_DIM;  // [B,S,S]

    short* qp  = (short*)d_ws;                    // [B*S,64] bf16 (Wq pre-scaled 1/64)
    short* kp  = qp + (size_t)MROWS * ATT_DIM;    // [B*S,64] bf16
    short* vpT = kp + (size_t)MROWS * ATT_DIM;    // [B][64][S] bf16
    short* Wbf = vpT + (size_t)MROWS * ATT_DIM;   // [3][64][1024] bf16

    wcvt_kernel<<<dim3(96), 256, 0, stream>>>(Wq, Wk, Wv, Wbf);

    proj_mfma_kernel<<<dim3(MROWS / 64, 3), 256, 0, stream>>>(
        q, k, v, Wbf, qp, kp, vpT);

    attn_kernel<<<dim3(SEQ / 16, BATCH), 512, 0, stream>>>(
        qp, kp, vpT, probs, att);
}